// Round 10
// baseline (665.415 us; speedup 1.0000x reference)
//
#include <hip/hip_runtime.h>

#define IMG 256
#define TSZ 128
#define TPB 128
#define TILES 2
#define NIMG 8
#define NBLK (NIMG * TILES * TILES)

// ctrl layout (unsigned words), zeroed via hipMemsetAsync before each launch:
// [0..23]  convergence tags: tag[img][recon] = ctrl[img*3 + rc]
// [24..31] per-image barrier arrival counters (monotone)
// [32] any1 flag   [33] any0 flag
// [34..41] CC per image
// [42] done counter (images finished)
// [48..79] per-tile ring-publish sequence rtag[img*4 + tin]
#define CTRL_WORDS 128

// Mailbox edges
#define ET 0
#define EB 1
#define EL 2
#define ER 3

// Swizzle: row r, col c -> r*128 + (c ^ (r&31)). Row walks and column walks
// both land <=2-way on the 32 banks (free on CDNA4 per m136).
__device__ __forceinline__ int swz(int r, int c) { return r * TSZ + (c ^ (r & 31)); }

__device__ __forceinline__ float agload(const float* p) {
  return __hip_atomic_load(p, __ATOMIC_RELAXED, __HIP_MEMORY_SCOPE_AGENT);
}
__device__ __forceinline__ void agstore(float* p, float v) {
  __hip_atomic_store(p, v, __ATOMIC_RELAXED, __HIP_MEMORY_SCOPE_AGENT);
}
__device__ __forceinline__ unsigned agloadu(const unsigned* p) {
  return __hip_atomic_load(p, __ATOMIC_RELAXED, __HIP_MEMORY_SCOPE_AGENT);
}

__device__ __forceinline__ float* mbp(float* mbox, int img, int tin, int e) {
  return mbox + (((img * 4 + tin) * 4 + e) * TSZ);
}

// 4-party per-image barrier: fence / arrive / spin / fence (r9-proven).
__device__ __forceinline__ void img_barrier(unsigned* bar, unsigned& gen, int tid) {
  __threadfence();
  __syncthreads();
  ++gen;
  if (tid == 0) {
    __hip_atomic_fetch_add(bar, 1u, __ATOMIC_RELAXED, __HIP_MEMORY_SCOPE_AGENT);
    while (__hip_atomic_load(bar, __ATOMIC_RELAXED, __HIP_MEMORY_SCOPE_AGENT) < 4u * gen)
      __builtin_amdgcn_s_sleep(1);
  }
  __syncthreads();
  __threadfence();
}

// Full ring publish (init / phase transitions): store mailbox + prevRing,
// bump seq, release-store rtag. Caller must __syncthreads() before (recS
// settled) and img_barrier after.
__device__ __forceinline__ void publish_full(float* recS, float* prevT, float* prevB,
                                             float* prevL, float* prevR, float* mbox,
                                             unsigned* rtags, unsigned& myseq,
                                             int img, int tin, int tid) {
  float tV = recS[swz(0, tid)],        bV = recS[swz(TSZ - 1, tid)];
  float lV = recS[swz(tid, 0)],        rV = recS[swz(tid, TSZ - 1)];
  agstore(&mbp(mbox, img, tin, ET)[tid], tV);
  agstore(&mbp(mbox, img, tin, EB)[tid], bV);
  agstore(&mbp(mbox, img, tin, EL)[tid], lV);
  agstore(&mbp(mbox, img, tin, ER)[tid], rV);
  prevT[tid] = tV; prevB[tid] = bV; prevL[tid] = lV; prevR[tid] = rV;
  ++myseq;
  __threadfence();
  __syncthreads();
  if (tid == 0)
    __hip_atomic_store(&rtags[tin], myseq, __ATOMIC_RELEASE, __HIP_MEMORY_SCOPE_AGENT);
}

// Geodesic reconstruction by dilation to exact fixpoint (r8/r9-proven sweeps).
// Coverage per iteration: H-fwd {W,N,S,NW,SW} + H-bwd {E,N,S,NE,SE} = all 8
// neighbors (racy-but-monotone reads <= fixpoint); V sweeps accelerate
// vertical propagation. Idle-skip: a tile whose last sweep was a no-op and
// whose neighbors' rings are unchanged (rtag acquire-check) skips staging and
// sweeping — exact, since identical halos reproduce the same fixpoint.
__device__ void recon(float* recS, float* maskS,
                      float* topH, float* botH, float* leftH, float* rightH,
                      float* prevT, float* prevB, float* prevL, float* prevR,
                      float* mbox, unsigned* rtags, unsigned* tag,
                      unsigned* bar, unsigned& gen, unsigned& myseq,
                      int img, int tin, int ty, int tx, int tid, int* flags) {
  const float NEGF = -__builtin_inff();
  const int oA = (tin == 0) ? 1 : 0;
  const int oB = (tin <= 1) ? 2 : 1;
  const int oC = (tin <= 2) ? 3 : 2;
  unsigned ls0 = 0, ls1 = 0, ls2 = 0;
  bool own_changed = true;
  for (unsigned it = 1;; ++it) {
    unsigned r0 = __hip_atomic_load(&rtags[oA], __ATOMIC_ACQUIRE, __HIP_MEMORY_SCOPE_AGENT);
    unsigned r1 = __hip_atomic_load(&rtags[oB], __ATOMIC_ACQUIRE, __HIP_MEMORY_SCOPE_AGENT);
    unsigned r2 = __hip_atomic_load(&rtags[oC], __ATOMIC_ACQUIRE, __HIP_MEMORY_SCOPE_AGENT);
    bool dowork = own_changed || (r0 > ls0) || (r1 > ls1) || (r2 > ls2);
    bool chg = false;
    if (dowork) {
      ls0 = r0; ls1 = r1; ls2 = r2;
      // ---- stage halos from neighbor mailboxes (contiguous, coalesced) ----
      topH[tid + 1]  = (ty > 0)         ? agload(&mbp(mbox, img, (ty - 1) * TILES + tx, EB)[tid]) : NEGF;
      botH[tid + 1]  = (ty < TILES - 1) ? agload(&mbp(mbox, img, (ty + 1) * TILES + tx, ET)[tid]) : NEGF;
      leftH[tid]     = (tx > 0)         ? agload(&mbp(mbox, img, ty * TILES + tx - 1, ER)[tid]) : NEGF;
      rightH[tid]    = (tx < TILES - 1) ? agload(&mbp(mbox, img, ty * TILES + tx + 1, EL)[tid]) : NEGF;
      if (tid == 0) topH[0]        = (ty > 0 && tx > 0)                 ? agload(&mbp(mbox, img, (ty - 1) * TILES + tx - 1, EB)[TSZ - 1]) : NEGF;
      if (tid == 1) topH[TSZ + 1]  = (ty > 0 && tx < TILES - 1)         ? agload(&mbp(mbox, img, (ty - 1) * TILES + tx + 1, EB)[0]) : NEGF;
      if (tid == 2) botH[0]        = (ty < TILES - 1 && tx > 0)         ? agload(&mbp(mbox, img, (ty + 1) * TILES + tx - 1, ET)[TSZ - 1]) : NEGF;
      if (tid == 3) botH[TSZ + 1]  = (ty < TILES - 1 && tx < TILES - 1) ? agload(&mbp(mbox, img, (ty + 1) * TILES + tx + 1, ET)[0]) : NEGF;
      __syncthreads();

      // ======== H phase: lane owns row r = tid; chunk-of-16 buffered ======
      {
        const int r = tid;
        const int xs = r & 31;
        float* rowS = &recS[r * TSZ];
        const float* mrow = &maskS[r * TSZ];
        const float* upB = (r == 0)       ? &topH[1] : &recS[(r - 1) * TSZ];
        const int upX    = (r == 0)       ? 0        : ((r - 1) & 31);
        const float* dnB = (r == TSZ - 1) ? &botH[1] : &recS[(r + 1) * TSZ];
        const int dnX    = (r == TSZ - 1) ? 0        : ((r + 1) & 31);
        // forward: W(carry) + N,S + NW,SW (pu/pd = prev-column up/dn)
        {
          float carry = leftH[r];
          float pu = (r == 0)       ? topH[0] : leftH[r - 1];
          float pd = (r == TSZ - 1) ? botH[0] : leftH[r + 1];
#pragma unroll 1
          for (int k = 0; k < 8; ++k) {
            const int c0 = k * 16;
            float o[16], mm[16], uu[16], dd[16];
#pragma unroll
            for (int i = 0; i < 16; ++i) {
              o[i]  = rowS[(c0 + i) ^ xs];
              mm[i] = mrow[(c0 + i) ^ xs];
              uu[i] = upB[(c0 + i) ^ upX];
              dd[i] = dnB[(c0 + i) ^ dnX];
            }
#pragma unroll
            for (int i = 0; i < 16; ++i) {
              float cand = fmaxf(fmaxf(fmaxf(uu[i], dd[i]), fmaxf(pu, pd)), carry);
              float v = fminf(mm[i], fmaxf(o[i], cand));
              chg |= (v > o[i]);
              o[i] = v; carry = v; pu = uu[i]; pd = dd[i];
            }
#pragma unroll
            for (int i = 0; i < 16; ++i) rowS[(c0 + i) ^ xs] = o[i];
          }
        }
        // backward: E(carry) + N,S + NE,SE
        {
          float carry = rightH[r];
          float pu = (r == 0)       ? topH[TSZ + 1] : rightH[r - 1];
          float pd = (r == TSZ - 1) ? botH[TSZ + 1] : rightH[r + 1];
#pragma unroll 1
          for (int k = 7; k >= 0; --k) {
            const int c0 = k * 16;
            float o[16], mm[16], uu[16], dd[16];
#pragma unroll
            for (int i = 0; i < 16; ++i) {
              o[i]  = rowS[(c0 + i) ^ xs];
              mm[i] = mrow[(c0 + i) ^ xs];
              uu[i] = upB[(c0 + i) ^ upX];
              dd[i] = dnB[(c0 + i) ^ dnX];
            }
#pragma unroll
            for (int i = 15; i >= 0; --i) {
              float cand = fmaxf(fmaxf(fmaxf(uu[i], dd[i]), fmaxf(pu, pd)), carry);
              float v = fminf(mm[i], fmaxf(o[i], cand));
              chg |= (v > o[i]);
              o[i] = v; carry = v; pu = uu[i]; pd = dd[i];
            }
#pragma unroll
            for (int i = 0; i < 16; ++i) rowS[(c0 + i) ^ xs] = o[i];
          }
        }
      }
      __syncthreads();
      // ======== V phase: lane owns column c = tid; chunk-of-16 buffered ====
      {
        const int c = tid;
        // forward (top -> bottom): N via live carry
        {
          float carry = topH[c + 1];
#pragma unroll 1
          for (int k = 0; k < 8; ++k) {
            const int r0i = k * 16;
            float o[16], mm[16];
#pragma unroll
            for (int i = 0; i < 16; ++i) {
              o[i]  = recS[swz(r0i + i, c)];
              mm[i] = maskS[swz(r0i + i, c)];
            }
#pragma unroll
            for (int i = 0; i < 16; ++i) {
              float v = fminf(mm[i], fmaxf(o[i], carry));
              chg |= (v > o[i]);
              o[i] = v; carry = v;
            }
#pragma unroll
            for (int i = 0; i < 16; ++i) recS[swz(r0i + i, c)] = o[i];
          }
        }
        // backward (bottom -> top): S via live carry
        {
          float carry = botH[c + 1];
#pragma unroll 1
          for (int k = 7; k >= 0; --k) {
            const int r0i = k * 16;
            float o[16], mm[16];
#pragma unroll
            for (int i = 0; i < 16; ++i) {
              o[i]  = recS[swz(r0i + i, c)];
              mm[i] = maskS[swz(r0i + i, c)];
            }
#pragma unroll
            for (int i = 15; i >= 0; --i) {
              float v = fminf(mm[i], fmaxf(o[i], carry));
              chg |= (v > o[i]);
              o[i] = v; carry = v;
            }
#pragma unroll
            for (int i = 0; i < 16; ++i) recS[swz(r0i + i, c)] = o[i];
          }
        }
      }
      __syncthreads();
    }

    // ---- vote chg; publish ring only if it actually changed ----
    if (tid == 0) { flags[0] = 0; flags[1] = 0; }
    __syncthreads();
    if (__any(chg ? 1 : 0) && (tid & 63) == 0) flags[0] = 1;
    __syncthreads();
    bool blockChanged = flags[0] != 0;
    if (blockChanged) {
      float tV = recS[swz(0, tid)],  bV = recS[swz(TSZ - 1, tid)];
      float lV = recS[swz(tid, 0)],  rV = recS[swz(tid, TSZ - 1)];
      bool diff = (__float_as_uint(tV) != __float_as_uint(prevT[tid])) |
                  (__float_as_uint(bV) != __float_as_uint(prevB[tid])) |
                  (__float_as_uint(lV) != __float_as_uint(prevL[tid])) |
                  (__float_as_uint(rV) != __float_as_uint(prevR[tid]));
      if (__any(diff ? 1 : 0) && (tid & 63) == 0) flags[1] = 1;
      __syncthreads();
      if (flags[1]) {
        agstore(&mbp(mbox, img, tin, ET)[tid], tV);
        agstore(&mbp(mbox, img, tin, EB)[tid], bV);
        agstore(&mbp(mbox, img, tin, EL)[tid], lV);
        agstore(&mbp(mbox, img, tin, ER)[tid], rV);
        prevT[tid] = tV; prevB[tid] = bV; prevL[tid] = lV; prevR[tid] = rV;
        ++myseq;
        __threadfence();
        __syncthreads();
        if (tid == 0)
          __hip_atomic_store(&rtags[tin], myseq, __ATOMIC_RELEASE, __HIP_MEMORY_SCOPE_AGENT);
      }
      if (tid == 0) atomicMax(tag, it);
    }
    img_barrier(bar, gen, tid);
    if (agloadu(tag) < it) break;  // uniform within image: tag>=it only if change
    own_changed = blockChanged;
  }
}

__global__ void __launch_bounds__(TPB)
hmax_kernel(const float* __restrict__ x, const float* __restrict__ hvec,
            const float* __restrict__ u, float* __restrict__ out,
            float* mbox, unsigned* ctrl) {
  extern __shared__ float lds[];
  float* recS   = lds;
  float* maskS  = lds + TSZ * TSZ;
  float* topH   = lds + 2 * TSZ * TSZ;
  float* botH   = topH + (TSZ + 2);
  float* leftH  = botH + (TSZ + 2);
  float* rightH = leftH + TSZ;
  float* prevT  = rightH + TSZ;
  float* prevB  = prevT + TSZ;
  float* prevL  = prevB + TSZ;
  float* prevR  = prevL + TSZ;
  __shared__ int flags[2];

  const int tid = threadIdx.x;
  const int blk = blockIdx.x;
  const int img = blk / (TILES * TILES);
  const int tin = blk % (TILES * TILES);
  const int ty = tin / TILES, tx = tin % TILES;
  const int R0 = ty * TSZ, C0 = tx * TSZ;
  const float* ximg = x + (size_t)img * IMG * IMG;
  const float* uimg = u + (size_t)img * IMG * IMG;
  unsigned* tag = &ctrl[img * 3];
  unsigned* bar = &ctrl[24 + img];
  unsigned* rtags = &ctrl[48 + img * 4];
  unsigned gen = 0;
  unsigned myseq = 0;

  // ---- init: mask = x, rec = x - h (LDS), publish ring ----
  const float hval = hvec[img];
  for (int rr = 0; rr < TSZ; ++rr) {
    float xv = ximg[(R0 + rr) * IMG + C0 + tid];
    maskS[swz(rr, tid)] = xv;
    recS[swz(rr, tid)] = xv - hval;
  }
  __syncthreads();
  publish_full(recS, prevT, prevB, prevL, prevR, mbox, rtags, myseq, img, tin, tid);
  img_barrier(bar, gen, tid);

  // ---- recon 1: xh = rho(x - h | x) ----
  recon(recS, maskS, topH, botH, leftH, rightH, prevT, prevB, prevL, prevR,
        mbox, rtags, &tag[0], bar, gen, myseq, img, tin, ty, tx, tid, flags);

  // ---- phase B: mask = xh, rec = xh - EPS, publish ring ----
  for (int rr = 0; rr < TSZ; ++rr) {
    int ix = swz(rr, tid);
    float xh = recS[ix];
    maskS[ix] = xh;
    recS[ix] = xh - 1e-05f;
  }
  __syncthreads();
  publish_full(recS, prevT, prevB, prevL, prevR, mbox, rtags, myseq, img, tin, tid);
  img_barrier(bar, gen, tid);

  // ---- recon 2: rho(xh - EPS | xh) ----
  recon(recS, maskS, topH, botH, leftH, rightH, prevT, prevB, prevL, prevR,
        mbox, rtags, &tag[1], bar, gen, myseq, img, tin, ty, tx, tid, flags);

  // ---- phase C: Rmax, marker = min(U, Rmax), publish ring ----
  bool a1 = false, a0 = false;
  for (int rr = 0; rr < TSZ; ++rr) {
    int ix = swz(rr, tid);
    float xh = maskS[ix];
    float r2 = recS[ix];
    float rm = (xh - r2 > 0.0f) ? 1.0f : 0.0f;
    a1 |= (rm == 1.0f);
    a0 |= (rm == 0.0f);
    float uv = uimg[(R0 + rr) * IMG + C0 + tid] / 100.0f;
    maskS[ix] = rm;
    recS[ix] = fminf(uv, rm);
  }
  if (__any(a1 ? 1 : 0) && (tid & 63) == 0)
    __hip_atomic_fetch_or(&ctrl[32], 1u, __ATOMIC_RELAXED, __HIP_MEMORY_SCOPE_AGENT);
  if (__any(a0 ? 1 : 0) && (tid & 63) == 0)
    __hip_atomic_fetch_or(&ctrl[33], 1u, __ATOMIC_RELAXED, __HIP_MEMORY_SCOPE_AGENT);
  __syncthreads();
  publish_full(recS, prevT, prevB, prevL, prevR, mbox, rtags, myseq, img, tin, tid);
  img_barrier(bar, gen, tid);

  // ---- recon 3: R = rho(min(U, Rmax) | Rmax) ----
  recon(recS, maskS, topH, botH, leftH, rightH, prevT, prevB, prevL, prevR,
        mbox, rtags, &tag[2], bar, gen, myseq, img, tin, ty, tx, tid, flags);

  // ---- phase D: count U == R per image ----
  unsigned cnt = 0;
  for (int rr = 0; rr < TSZ; ++rr) {
    float Rv = recS[swz(rr, tid)];
    float uv = uimg[(R0 + rr) * IMG + C0 + tid] / 100.0f;
    cnt += (uv == Rv) ? 1u : 0u;
  }
  for (int off = 32; off > 0; off >>= 1) cnt += __shfl_down(cnt, off, 64);
  if ((tid & 63) == 0)
    __hip_atomic_fetch_add(&ctrl[34 + img], cnt, __ATOMIC_RELAXED, __HIP_MEMORY_SCOPE_AGENT);
  img_barrier(bar, gen, tid);  // all 4 blocks' CC adds done (entry fence)

  if (tin == 0 && tid == 0)
    __hip_atomic_fetch_add(&ctrl[42], 1u, __ATOMIC_RELEASE, __HIP_MEMORY_SCOPE_AGENT);

  // ---- final join + output (block 0 only; co-resident via coop launch) ----
  if (blk == 0) {
    if (tid == 0) {
      while (__hip_atomic_load(&ctrl[42], __ATOMIC_RELAXED, __HIP_MEMORY_SCOPE_AGENT) < NIMG)
        __builtin_amdgcn_s_sleep(1);
    }
    __syncthreads();
    __threadfence();
    if (tid < NIMG) {
      float CC = (float)agloadu(&ctrl[34 + tid]);
      float gmax = agloadu(&ctrl[32]) ? 1.0f : 0.0f;
      float gmin = agloadu(&ctrl[33]) ? 0.0f : 1.0f;
      float d = gmax - gmin;
      out[tid] = fminf(CC, 100.0f * d * CC);
    }
  }
}

extern "C" void kernel_launch(void* const* d_in, const int* in_sizes, int n_in,
                              void* d_out, int out_size, void* d_ws, size_t ws_size,
                              hipStream_t stream) {
  const float* x = (const float*)d_in[0];
  const float* h = (const float*)d_in[1];
  const float* u = (const float*)d_in[2];
  float* out = (float*)d_out;
  float* mbox = (float*)d_ws;  // NIMG*4tiles*4edges*TSZ floats = 64 KB
  unsigned* ctrl = (unsigned*)((char*)d_ws + (size_t)NIMG * 4 * 4 * TSZ * sizeof(float));

  hipMemsetAsync(ctrl, 0, CTRL_WORDS * sizeof(unsigned), stream);

  const unsigned SH = (2 * TSZ * TSZ + 2 * (TSZ + 2) + 6 * TSZ) * sizeof(float);
  hipFuncSetAttribute((const void*)hmax_kernel,
                      hipFuncAttributeMaxDynamicSharedMemorySize, (int)SH);

  void* args[] = { (void*)&x, (void*)&h, (void*)&u, (void*)&out,
                   (void*)&mbox, (void*)&ctrl };
  hipLaunchCooperativeKernel((void*)hmax_kernel, dim3(NBLK), dim3(TPB),
                             args, SH, stream);
}